// Round 4
// baseline (145.830 us; speedup 1.0000x reference)
//
#include <hip/hip_runtime.h>

// ---------------------------------------------------------------------------
// ConvQuantizationWrapper: exact integer reformulation, MFMA i8, pixel-linear.
// out = [conv3x3(q_in, tc(q_w)) + zp*conv3x3(ones, q_w)] / (sa*sw) + bias
//   q_in = clip(round(x*sa - zp), 0, 255) (u8);  q_w = round(w*sw)
// qa holds (q_in - 128) i8 in zero-padded NHWC [n][58][58][64c].
// conv: v_mfma_i32_16x16x64_i8 (K = full 64-channel dim per instruction),
// M = 16 flat pixels per tile (px = h*56+w; row crossings fine: qa addressing
// affine in (kh,kw), out px-linear per (n,o)). N = 16 och per wave.
// Border correction via inclusion-exclusion on per-(o,tap) channel-sum tables.
// ---------------------------------------------------------------------------

typedef int v4i __attribute__((ext_vector_type(4)));

#define QA_ROW   3712        // 58 cols * 64 B
#define QA_IMG   215296      // 58 rows * QA_ROW
#define QA_BYTES 13778944    // 64 images

// ---- fused weight prep: quantize + per-(o,tap) channel sums (wave reduce) ----
__global__ __launch_bounds__(64) void prep_wq(const float* __restrict__ wt,
                                              const float* __restrict__ sw_p,
                                              signed char* __restrict__ w8,
                                              int* __restrict__ Qtc,
                                              int* __restrict__ Qraw) {
  const int o = blockIdx.x;             // 0..63
  const int i = threadIdx.x;            // input channel 0..63
  const float sw = sw_p[0];
  const float* wp = wt + (size_t)(o * 64 + i) * 9;
  int q[9];
#pragma unroll
  for (int k = 0; k < 9; ++k) q[k] = (int)rintf(wp[k] * sw);
#pragma unroll
  for (int k = 0; k < 9; ++k)
    w8[(o * 9 + k) * 64 + i] = (signed char)(q[k] & 255);
#pragma unroll
  for (int k = 0; k < 9; ++k) {
    int stc = (int)(signed char)(q[k] & 255);   // two's-complement i8 value
    int srw = q[k];
#pragma unroll
    for (int off = 32; off; off >>= 1) {
      stc += __shfl_xor(stc, off);
      srw += __shfl_xor(srw, off);
    }
    if (i == 0) { Qtc[o * 9 + k] = stc; Qraw[o * 9 + k] = srw; }
  }
}

// ---- quantize activations: NCHW fp32 -> padded NHWC i8 (q_in - 128) ----
// 2 rows per block; float4 coalesced loads, LDS byte-transpose (stride 68).
__global__ __launch_bounds__(256) void quant_a(const float* __restrict__ x,
                                               const float* __restrict__ sa_p,
                                               const float* __restrict__ zp_p,
                                               signed char* __restrict__ qa) {
  __shared__ int ldsbuf[1904];          // 2 * 56 * 68 bytes
  signed char* lds = (signed char*)ldsbuf;
  const int bx = blockIdx.x;            // 0..27 -> rows 2bx, 2bx+1
  const int n = blockIdx.y;
  const int t = threadIdx.x;
  const float sa = sa_p[0], zp = zp_p[0];
  const float* xim = x + (size_t)n * 200704;    // 64 * 3136
  const int h0 = bx * 2;

#pragma unroll
  for (int it = 0; it < 7; ++it) {
    const int idx = t + 256 * it;       // 0..1791: [r][c][w4]
    const int r = idx >= 896;
    const int rem = idx - 896 * r;
    const int c = (rem * 2341) >> 15;   // rem / 14  (exact for rem < 896)
    const int w4 = rem - c * 14;
    const float4 v = *(const float4*)(xim + (size_t)c * 3136 + (h0 + r) * 56 + w4 * 4);
    signed char* dst = lds + r * 3808 + w4 * 272 + c;   // [(4*w4+e)*68 + c]
    const float vv[4] = {v.x, v.y, v.z, v.w};
#pragma unroll
    for (int e = 0; e < 4; ++e) {
      float tq;
      {
#pragma clang fp contract(off)
        tq = vv[e] * sa - zp;           // match ref: mul then sub, no fma
      }
      float qf = rintf(tq);             // half-to-even, like jnp.round
      qf = fminf(fmaxf(qf, 0.0f), 255.0f);
      dst[e * 68] = (signed char)((int)qf - 128);
    }
  }
  __syncthreads();

  signed char* const qim = qa + (size_t)n * QA_IMG;
#pragma unroll
  for (int it = 0; it < 2; ++it) {
    const int idx = t + 256 * it;
    if (idx < 448) {                    // interior: 2 rows x 56 cols x 16B quads
      const int r = idx >= 224;
      const int u = idx - 224 * r;
      const int w = u >> 2, q2 = u & 3;
      const unsigned* s = (const unsigned*)(lds + r * 3808 + w * 68 + q2 * 16);
      const uint4 vv = make_uint4(s[0], s[1], s[2], s[3]);
      *((uint4*)(qim + (size_t)(h0 + r + 1) * QA_ROW + (w + 1) * 64 + q2 * 16)) = vv;
    } else if (idx < 464) {             // col pads: col 0 and col 57, both rows
      const int p = idx - 448;
      const int r = p >> 3;
      const int side = (p >> 2) & 1;
      const int j = p & 3;
      *((uint4*)(qim + (size_t)(h0 + r + 1) * QA_ROW + side * 57 * 64 + j * 16)) =
          make_uint4(0, 0, 0, 0);
    }
  }
  if (bx == 0 && t < 232)               // top pad row
    ((uint4*)qim)[t] = make_uint4(0, 0, 0, 0);
  if (bx == 27 && t < 232)              // bottom pad row
    ((uint4*)(qim + (size_t)57 * QA_ROW))[t] = make_uint4(0, 0, 0, 0);
}

// ---- main conv: implicit GEMM on v_mfma_i32_16x16x64_i8 ----
// block = 4 waves = 4 och groups of 16; block covers one n and 64 flat px.
// wave: 4 M-tiles of 16 px, each = 9 A-loads + 9 MFMAs (K=64) + epilogue.
// grid (49, 64): 49*64 = 3136 px exact, no M waste.
__global__ __launch_bounds__(256, 4) void conv_mfma(
    const signed char* __restrict__ qa, const signed char* __restrict__ w8,
    const int* __restrict__ Qtc, const int* __restrict__ Qraw,
    const float* __restrict__ bias, const float* __restrict__ sa_p,
    const float* __restrict__ sw_p, const float* __restrict__ zp_p,
    float* __restrict__ out) {
  const int tid = threadIdx.x;
  const int lane = tid & 63;
  const int og = tid >> 6;              // och group 0..3
  const int n = blockIdx.y;
  const int p0 = blockIdx.x * 64;
  const int ln = lane & 15;
  const int kg = lane >> 4;             // k-group: bytes kg*16..kg*16+15
  const int o = og * 16 + ln;

  // B fragments: B[n=ln][k = kg*16 + j] per tap
  const signed char* wbp = w8 + (size_t)o * 576 + kg * 16;
  v4i B[9];
#pragma unroll
  for (int tp = 0; tp < 9; ++tp) B[tp] = *(const v4i*)(wbp + tp * 64);

  // per-tap correction values: 128*Qtc + zp*Qraw
  const float sa = sa_p[0], sw = sw_p[0], zp = zp_p[0];
  float ct[9];
#pragma unroll
  for (int k = 0; k < 9; ++k)
    ct[k] = 128.0f * (float)Qtc[o * 9 + k] + zp * (float)Qraw[o * 9 + k];
  const float Full = ct[0] + ct[1] + ct[2] + ct[3] + ct[4] + ct[5] + ct[6] + ct[7] + ct[8];
  const float Rtop = ct[0] + ct[1] + ct[2];   // removed when h == 0
  const float Rbot = ct[6] + ct[7] + ct[8];   // removed when h == 55
  const float Clft = ct[0] + ct[3] + ct[6];   // removed when w == 0
  const float Crgt = ct[2] + ct[5] + ct[8];   // removed when w == 55
  const float c0 = ct[0], c2 = ct[2], c6 = ct[6], c8 = ct[8];
  const float rden = 1.0f / (sw * sa);
  const float bo = bias[o];

  const signed char* qim = qa + (size_t)n * QA_IMG + kg * 16;
  float* const obase = out + (size_t)(n * 64 + o) * 3136;

#pragma unroll 1
  for (int t = 0; t < 4; ++t) {
    // A row pixel for this lane (m = ln), tile base p0 + t*16
    const int pxa = p0 + t * 16 + ln;
    const int hp = (pxa * 9363) >> 19;  // pxa / 56 (exact for pxa < 3136)
    const int wp = pxa - hp * 56;
    const signed char* abase = qim + (hp * 58 + wp) * 64;
    v4i A[9];
#pragma unroll
    for (int kh = 0; kh < 3; ++kh)
#pragma unroll
      for (int kw = 0; kw < 3; ++kw)
        A[kh * 3 + kw] = *(const v4i*)(abase + kh * QA_ROW + kw * 64);

    v4i acc = {0, 0, 0, 0};
#pragma unroll
    for (int k = 0; k < 9; ++k)
      acc = __builtin_amdgcn_mfma_i32_16x16x64_i8(A[k], B[k], acc, 0, 0, 0);

    // epilogue: C/D row(px) = kg*4 + reg, col(och) = ln
    const int pxb = p0 + t * 16 + kg * 4;
    const int hb = (pxb * 9363) >> 19;
    const int wb2 = pxb - hb * 56;
    float tmp[4];
    if (hb >= 1 && hb <= 54 && wb2 >= 1 && wb2 <= 51) {
      // fast path: all 4 px interior, same row
#pragma unroll
      for (int e = 0; e < 4; ++e)
        tmp[e] = ((float)acc[e] + Full) * rden + bo;
    } else {
#pragma unroll
      for (int e = 0; e < 4; ++e) {
        const int p = pxb + e;
        const int h = (p * 9363) >> 19;
        const int w = p - h * 56;
        const bool tb = (h == 0), bb = (h == 55), lb = (w == 0), rb = (w == 55);
        float corr = Full;
        corr -= tb ? Rtop : 0.0f;
        corr -= bb ? Rbot : 0.0f;
        corr -= lb ? Clft : 0.0f;
        corr -= rb ? Crgt : 0.0f;
        corr += (tb && lb) ? c0 : 0.0f;  // corner overlaps added back
        corr += (tb && rb) ? c2 : 0.0f;
        corr += (bb && lb) ? c6 : 0.0f;
        corr += (bb && rb) ? c8 : 0.0f;
        tmp[e] = ((float)acc[e] + corr) * rden + bo;
      }
    }
    float4 vv;
    vv.x = tmp[0]; vv.y = tmp[1]; vv.z = tmp[2]; vv.w = tmp[3];
    *(float4*)(obase + pxb) = vv;
  }
}

extern "C" void kernel_launch(void* const* d_in, const int* in_sizes, int n_in,
                              void* d_out, int out_size, void* d_ws, size_t ws_size,
                              hipStream_t stream) {
  const float* x    = (const float*)d_in[0];
  const float* wt   = (const float*)d_in[1];
  const float* bias = (const float*)d_in[2];
  const float* sa   = (const float*)d_in[3];
  const float* sw   = (const float*)d_in[4];
  const float* zp   = (const float*)d_in[5];
  float* out = (float*)d_out;

  char* ws = (char*)d_ws;
  signed char* qa = (signed char*)ws;                       // QA_BYTES
  signed char* w8 = (signed char*)(ws + QA_BYTES);          // 36,864 B
  int* Qtc  = (int*)(ws + QA_BYTES + 36864);                // 2,304 B
  int* Qraw = (int*)(ws + QA_BYTES + 36864 + 2304);         // 2,304 B

  prep_wq<<<64, 64, 0, stream>>>(wt, sw, w8, Qtc, Qraw);
  quant_a<<<dim3(28, 64), 256, 0, stream>>>(x, sa, zp, qa);
  conv_mfma<<<dim3(49, 64), 256, 0, stream>>>(qa, w8, Qtc, Qraw, bias, sa, sw, zp, out);
}

// Round 5
// 124.900 us; speedup vs baseline: 1.1676x; 1.1676x over previous
//
#include <hip/hip_runtime.h>

// ---------------------------------------------------------------------------
// ConvQuantizationWrapper: exact integer reformulation, MFMA i8, LDS-staged.
// out = [conv3x3(q_in, tc(q_w)) + zp*conv3x3(ones, q_w)] / (sa*sw) + bias
//   q_in = clip(round(x*sa - zp), 0, 255) (u8);  q_w = round(w*sw)
// qa holds (q_in - 128) i8 in zero-padded NHWC [n][58][58][64c].
// conv: block stages 6 qa rows into LDS (coalesced -> kills the L1 line-
// transaction bottleneck measured in R4: per-lane 16B gathers = 16 lines per
// wave instr, ~38K lines/CU = 43us). A frags come from ds_read_b128 and each
// feeds TWO 16-och MFMAs (halves LDS reads). Border corrections via a 9-case
// x 64-och table (built in prep_wq) staged into LDS.
// ---------------------------------------------------------------------------

typedef int v4i __attribute__((ext_vector_type(4)));

#define QA_ROW   3712        // 58 cols * 64 B
#define QA_IMG   215296      // 58 rows * QA_ROW
#define QA_BYTES 13778944    // 64 images

// ---- fused weight prep: quantize + 9-case border-correction table ----
// corr_tab[case][o], case = vcase*3 + hcase; vcase: 0 interior, 1 top(h==0),
// 2 bottom(h==55); hcase: 0 interior, 1 left(w==0), 2 right(w==55).
// corr = sum over in-range taps of (128*sum_c tc(q_w) + zp*sum_c q_w).
__global__ __launch_bounds__(64) void prep_wq(const float* __restrict__ wt,
                                              const float* __restrict__ sw_p,
                                              const float* __restrict__ zp_p,
                                              signed char* __restrict__ w8,
                                              float* __restrict__ corr_tab) {
  const int o = blockIdx.x;             // 0..63
  const int i = threadIdx.x;            // input channel 0..63
  const float sw = sw_p[0];
  const float* wp = wt + (size_t)(o * 64 + i) * 9;
  int q[9];
#pragma unroll
  for (int k = 0; k < 9; ++k) q[k] = (int)rintf(wp[k] * sw);
#pragma unroll
  for (int k = 0; k < 9; ++k)
    w8[(o * 9 + k) * 64 + i] = (signed char)(q[k] & 255);

  int stc[9], srw[9];
#pragma unroll
  for (int k = 0; k < 9; ++k) {
    int a = (int)(signed char)(q[k] & 255);   // two's-complement i8 value
    int b = q[k];
#pragma unroll
    for (int off = 32; off; off >>= 1) {      // xor butterfly: sum in ALL lanes
      a += __shfl_xor(a, off);
      b += __shfl_xor(b, off);
    }
    stc[k] = a; srw[k] = b;
  }
  const float zp = zp_p[0];
  if (i < 9) {                          // lane i computes border case i
    const int v = i / 3, hc = i % 3;
    float corr = 0.0f;
#pragma unroll
    for (int k = 0; k < 9; ++k) {
      const int kh = k / 3, kw = k % 3;
      const bool drop = (v == 1 && kh == 0) || (v == 2 && kh == 2) ||
                        (hc == 1 && kw == 0) || (hc == 2 && kw == 2);
      if (!drop) corr += 128.0f * (float)stc[k] + zp * (float)srw[k];
    }
    corr_tab[i * 64 + o] = corr;
  }
}

// ---- quantize activations: NCHW fp32 -> padded NHWC i8 (q_in - 128) ----
// 2 rows per block; float4 coalesced loads, LDS byte-transpose (stride 68).
__global__ __launch_bounds__(256) void quant_a(const float* __restrict__ x,
                                               const float* __restrict__ sa_p,
                                               const float* __restrict__ zp_p,
                                               signed char* __restrict__ qa) {
  __shared__ int ldsbuf[1904];          // 2 * 56 * 68 bytes
  signed char* lds = (signed char*)ldsbuf;
  const int bx = blockIdx.x;            // 0..27 -> rows 2bx, 2bx+1
  const int n = blockIdx.y;
  const int t = threadIdx.x;
  const float sa = sa_p[0], zp = zp_p[0];
  const float* xim = x + (size_t)n * 200704;    // 64 * 3136
  const int h0 = bx * 2;

#pragma unroll
  for (int it = 0; it < 7; ++it) {
    const int idx = t + 256 * it;       // 0..1791: [r][c][w4]
    const int r = idx >= 896;
    const int rem = idx - 896 * r;
    const int c = (rem * 2341) >> 15;   // rem / 14  (exact for rem < 896)
    const int w4 = rem - c * 14;
    const float4 v = *(const float4*)(xim + (size_t)c * 3136 + (h0 + r) * 56 + w4 * 4);
    signed char* dst = lds + r * 3808 + w4 * 272 + c;   // [(4*w4+e)*68 + c]
    const float vv[4] = {v.x, v.y, v.z, v.w};
#pragma unroll
    for (int e = 0; e < 4; ++e) {
      float tq;
      {
#pragma clang fp contract(off)
        tq = vv[e] * sa - zp;           // match ref: mul then sub, no fma
      }
      float qf = rintf(tq);             // half-to-even, like jnp.round
      qf = fminf(fmaxf(qf, 0.0f), 255.0f);
      dst[e * 68] = (signed char)((int)qf - 128);
    }
  }
  __syncthreads();

  signed char* const qim = qa + (size_t)n * QA_IMG;
#pragma unroll
  for (int it = 0; it < 2; ++it) {
    const int idx = t + 256 * it;
    if (idx < 448) {                    // interior: 2 rows x 56 cols x 16B quads
      const int r = idx >= 224;
      const int u = idx - 224 * r;
      const int w = u >> 2, q2 = u & 3;
      const unsigned* s = (const unsigned*)(lds + r * 3808 + w * 68 + q2 * 16);
      const uint4 vv = make_uint4(s[0], s[1], s[2], s[3]);
      *((uint4*)(qim + (size_t)(h0 + r + 1) * QA_ROW + (w + 1) * 64 + q2 * 16)) = vv;
    } else if (idx < 464) {             // col pads: col 0 and col 57, both rows
      const int p = idx - 448;
      const int r = p >> 3;
      const int side = (p >> 2) & 1;
      const int j = p & 3;
      *((uint4*)(qim + (size_t)(h0 + r + 1) * QA_ROW + side * 57 * 64 + j * 16)) =
          make_uint4(0, 0, 0, 0);
    }
  }
  if (bx == 0 && t < 232)               // top pad row
    ((uint4*)qim)[t] = make_uint4(0, 0, 0, 0);
  if (bx == 27 && t < 232)              // bottom pad row
    ((uint4*)(qim + (size_t)57 * QA_ROW))[t] = make_uint4(0, 0, 0, 0);
}

// ---- main conv: LDS-staged implicit GEMM on v_mfma_i32_16x16x64_i8 ----
// grid (14, 64): block = one n, 4 output rows (224 px), all 64 och.
// 4 waves = (px-half 0/1) x (och-pair 0/1). Wave: 7 M-tiles of 16 px; per
// tile 9 ds_read_b128 A-frags, each feeding 2 MFMAs (och groups oa, oa+16).
__global__ __launch_bounds__(256, 4) void conv_mfma(
    const signed char* __restrict__ qa, const signed char* __restrict__ w8,
    const float* __restrict__ corr_tab, const float* __restrict__ bias,
    const float* __restrict__ sa_p, const float* __restrict__ sw_p,
    float* __restrict__ out) {
  __shared__ __align__(16) signed char lds[24576];  // 6*58*64 qa + 9*64*4 corr
  const int tid = threadIdx.x;
  const int n = blockIdx.y;
  const int h0 = blockIdx.x * 4;        // output rows h0..h0+3; qa rows h0..h0+5

  // stage qa rows (22,272 B = 1392 uint4) + corr table (2,304 B = 144 uint4)
  {
    const uint4* src = (const uint4*)(qa + (size_t)n * QA_IMG + (size_t)h0 * QA_ROW);
    const uint4* csrc = (const uint4*)corr_tab;
    uint4* dst = (uint4*)lds;
#pragma unroll
    for (int it = 0; it < 6; ++it) {    // 1536 = 6 * 256 exactly
      const int idx = tid + it * 256;
      uint4 v;
      if (idx < 1392) v = src[idx];
      else v = csrc[idx - 1392];
      dst[idx] = v;
    }
  }
  __syncthreads();

  const int lane = tid & 63;
  const int wv = tid >> 6;
  const int phalf = wv & 1;             // px offset 112*phalf
  const int ogp = wv >> 1;              // och 32*ogp
  const int ln = lane & 15;
  const int kg = lane >> 4;             // k-group: bytes kg*16..kg*16+15
  const int oa = ogp * 32 + ln;         // first och; second is oa+16

  // B fragments for both och groups: B[n=ln][k = kg*16 + j] per tap
  const signed char* wba = w8 + (size_t)oa * 576 + kg * 16;
  v4i Ba[9], Bb[9];
#pragma unroll
  for (int t = 0; t < 9; ++t) {
    Ba[t] = *(const v4i*)(wba + t * 64);
    Bb[t] = *(const v4i*)(wba + 9216 + t * 64);   // (oa+16)*576
  }

  const float sa = sa_p[0], sw = sw_p[0];
  const float rden = 1.0f / (sw * sa);
  const float boa = bias[oa], bob = bias[oa + 16];
  const float* ctab = (const float*)(lds + 22272);
  const float cFa = ctab[oa];           // interior (case 0) corrections
  const float cFb = ctab[oa + 16];
  float* const outa = out + (size_t)(n * 64 + oa) * 3136 + h0 * 56;
  float* const outb = outa + 16 * 3136;

#pragma unroll 1
  for (int t = 0; t < 7; ++t) {
    const int pb = phalf * 112 + t * 16;          // block-relative px tile base
    const int pa = pb + ln;                       // this lane's A-row px (0..223)
    const int hr = (pa * 9363) >> 19;             // pa / 56 (exact)
    const int wc = pa - hr * 56;
    const signed char* ab = lds + (hr * 58 + wc) * 64 + kg * 16;
    v4i acca = {0, 0, 0, 0}, accb = {0, 0, 0, 0};
#pragma unroll
    for (int kh = 0; kh < 3; ++kh) {
#pragma unroll
      for (int kw = 0; kw < 3; ++kw) {
        const v4i A = *(const v4i*)(ab + (kh * 58 + kw) * 64);
        acca = __builtin_amdgcn_mfma_i32_16x16x64_i8(A, Ba[kh * 3 + kw], acca, 0, 0, 0);
        accb = __builtin_amdgcn_mfma_i32_16x16x64_i8(A, Bb[kh * 3 + kw], accb, 0, 0, 0);
      }
    }
    // epilogue: C/D row(px) = kg*4 + reg, col(och) = ln
    const int pxb = pb + kg * 4;
    float ta[4], tb[4];
#pragma unroll
    for (int e = 0; e < 4; ++e) {
      const int p = pxb + e;
      const int hh = (p * 9363) >> 19;
      const int ww = p - hh * 56;
      const int hg = h0 + hh;
      float ca = cFa, cb = cFb;
      if ((hg == 0) | (hg == 55) | (ww == 0) | (ww == 55)) {   // rare border
        const int vcase = (hg == 0) ? 1 : ((hg == 55) ? 2 : 0);
        const int hcase = (ww == 0) ? 1 : ((ww == 55) ? 2 : 0);
        const int cidx = (vcase * 3 + hcase) * 64;
        ca = ctab[cidx + oa];
        cb = ctab[cidx + oa + 16];
      }
      ta[e] = ((float)acca[e] + ca) * rden + boa;
      tb[e] = ((float)accb[e] + cb) * rden + bob;
    }
    *(float4*)(outa + pxb) = make_float4(ta[0], ta[1], ta[2], ta[3]);
    *(float4*)(outb + pxb) = make_float4(tb[0], tb[1], tb[2], tb[3]);
  }
}

extern "C" void kernel_launch(void* const* d_in, const int* in_sizes, int n_in,
                              void* d_out, int out_size, void* d_ws, size_t ws_size,
                              hipStream_t stream) {
  const float* x    = (const float*)d_in[0];
  const float* wt   = (const float*)d_in[1];
  const float* bias = (const float*)d_in[2];
  const float* sa   = (const float*)d_in[3];
  const float* sw   = (const float*)d_in[4];
  const float* zp   = (const float*)d_in[5];
  float* out = (float*)d_out;

  char* ws = (char*)d_ws;
  signed char* qa = (signed char*)ws;                       // QA_BYTES
  signed char* w8 = (signed char*)(ws + QA_BYTES);          // 36,864 B
  float* corr_tab = (float*)(ws + QA_BYTES + 36864);        // 2,304 B

  prep_wq<<<64, 64, 0, stream>>>(wt, sw, zp, w8, corr_tab);
  quant_a<<<dim3(28, 64), 256, 0, stream>>>(x, sa, zp, qa);
  conv_mfma<<<dim3(14, 64), 256, 0, stream>>>(qa, w8, corr_tab, bias, sa, sw, out);
}